// Round 8
// baseline (137.122 us; speedup 1.0000x reference)
//
#include <hip/hip_runtime.h>
#include <hip/hip_bf16.h>

// DiffRenderer v8: operand-swapped MFMA (D = Font . Probs) -> direct stores.
// Rounds 5-7 post-mortem: fences (v6) and logits coalescing (v7) both null;
// three structures all at 122us = 4.45 TB/s eff (floor ~80us @ copy-mix BW).
// Last unablated structure: the per-h LDS transpose round-trip. v8 kills it:
// A = font h-tile (M=16 w-px, zero-padded), B = probs (N=16 cells). D-layout
// (col=lane&15=cell, row=crow4+j=w) gives each lane 4 consecutive pixels of
// one cell -> wave stores a contiguous 3584B span per h straight from accs
// (2x float2 per mt; crow4==12 lanes store only w=12,13). Steady-state loop
// has NO LDS ops; LDS = 13.3KB prob buffer only (12 blocks/CU).
#define ROWS 384
#define COLS 768
#define NCH  69
#define CH   28
#define CW   14
#define KP   96             // K padded to 3 MFMA k-steps of 32
#define IMG_W 10752
#define ROW_U 104           // prob-row stride in ushorts (208B, 16B-aligned)

typedef __attribute__((ext_vector_type(8))) short bfrag;   // 8 bf16 (4 VGPR)
typedef __attribute__((ext_vector_type(4))) float f32x4;   // C/D frag

__device__ __forceinline__ unsigned bf16bits(float x) {
    unsigned b = __float_as_uint(x);
    b += 0x7FFFu + ((b >> 16) & 1u);   // RTNE
    return b >> 16;
}

// ---- kernel 1: font (69,28,14) f32 -> Fh[28][16][96] bf16 (w zero-padded) ----
__global__ __launch_bounds__(256)
void font_prep(const float* __restrict__ font, unsigned short* __restrict__ Fh) {
    int idx = blockIdx.x * 256 + threadIdx.x;        // 28*16*96 = 43008
    if (idx >= CH * 16 * KP) return;
    int k  = idx % KP;
    int hw = idx / KP;
    int w  = hw % 16, h = hw / 16;
    float v = (w < CW && k < NCH) ? font[k * (CH * CW) + h * CW + w] : 0.f;
    Fh[idx] = (unsigned short)bf16bits(v);
}

// ---- kernel 2: softmax + operand-swapped MFMA + direct stores ----
__global__ __launch_bounds__(64)
void diffrender_v8(const float* __restrict__ logits,       // (294912,69) f32
                   const unsigned short* __restrict__ Fh,  // (28,16,96) bf16
                   float* __restrict__ out)                // (10752,10752) f32
{
    __shared__ __align__(16) unsigned short Pa[64 * ROW_U]; // 13312 B

    const int lane = threadIdx.x;
    const int bid  = blockIdx.x;
    const int r    = bid / 12;                 // cell row (12 blocks/row)
    const int cb   = (bid % 12) * 64;          // first cell col of this block
    const int cell = bid * 64 + lane;

    // ---- per-thread softmax over 69 logits (per-lane loads: v7 proved free) ----
    const float* lp = logits + (size_t)cell * NCH;
    float e[NCH];
    float m = -INFINITY;
#pragma unroll
    for (int n = 0; n < NCH; ++n) { e[n] = lp[n]; m = fmaxf(m, e[n]); }
    float s = 0.f;
#pragma unroll
    for (int n = 0; n < NCH; ++n) { e[n] = __expf(e[n] - m); s += e[n]; }
    const float inv = 1.f / s;

    // ---- pack probs bf16 -> LDS row `lane` (k 0..95, zero-padded) ----
    unsigned* prow = (unsigned*)&Pa[(size_t)lane * ROW_U];
#pragma unroll
    for (int i = 0; i < 34; ++i)
        prow[i] = bf16bits(e[2 * i] * inv) | (bf16bits(e[2 * i + 1] * inv) << 16);
    prow[34] = bf16bits(e[68] * inv);
#pragma unroll
    for (int i = 35; i < 48; ++i) prow[i] = 0;
    // cross-lane frag reads below: compiler orders same-object LDS ops (v6-proven)

    // ---- B-frags (probs): 4 cell-groups x 3 k-steps, held all kernel ----
    const int c15   = lane & 15;               // B col = cell within group
    const int kgrp  = (lane >> 4) * 8;         // k-slice base
    const int crow4 = (lane >> 4) * 4;         // D row base = w base
    bfrag b[4][3];
#pragma unroll
    for (int mt = 0; mt < 4; ++mt)
#pragma unroll
        for (int ks = 0; ks < 3; ++ks)
            b[mt][ks] = *(const bfrag*)&Pa[(size_t)(mt * 16 + c15) * ROW_U + ks * 32 + kgrp];

    // ---- h loop: A = font tile (rows = w, zero-padded), double-buffered ----
    const unsigned short* fb = Fh + (size_t)c15 * KP + kgrp;  // + h*16*KP + ks*32
    bfrag acur[3], anxt[3];
#pragma unroll
    for (int ks = 0; ks < 3; ++ks)
        acur[ks] = *(const bfrag*)(fb + ks * 32);

#pragma unroll 2
    for (int h = 0; h < CH; ++h) {
        if (h + 1 < CH) {
            const unsigned short* fn = fb + (size_t)(h + 1) * 16 * KP;
#pragma unroll
            for (int ks = 0; ks < 3; ++ks)
                anxt[ks] = *(const bfrag*)(fn + ks * 32);
        }

        f32x4 acc[4] = {f32x4{0,0,0,0}, f32x4{0,0,0,0}, f32x4{0,0,0,0}, f32x4{0,0,0,0}};
#pragma unroll
        for (int mt = 0; mt < 4; ++mt)
#pragma unroll
            for (int ks = 0; ks < 3; ++ks)
                acc[mt] = __builtin_amdgcn_mfma_f32_16x16x32_bf16(acur[ks], b[mt][ks], acc[mt], 0, 0, 0);

        // ---- direct stores: lane owns cell (cb+mt*16+c15), pixels w=crow4..+3 ----
        float* orow = out + (size_t)(r * CH + h) * IMG_W;
#pragma unroll
        for (int mt = 0; mt < 4; ++mt) {
            float* p = orow + (size_t)(cb + mt * 16 + c15) * CW + crow4;
            *(float2*)p = make_float2(acc[mt][0], acc[mt][1]);
            if (crow4 < 12)                      // w=14,15 are pad rows
                *(float2*)(p + 2) = make_float2(acc[mt][2], acc[mt][3]);
        }

#pragma unroll
        for (int ks = 0; ks < 3; ++ks) acur[ks] = anxt[ks];
    }
}

extern "C" void kernel_launch(void* const* d_in, const int* in_sizes, int n_in,
                              void* d_out, int out_size, void* d_ws, size_t ws_size,
                              hipStream_t stream) {
    const float* logits = (const float*)d_in[0];   // (384,768,69) f32
    const float* font   = (const float*)d_in[1];   // (69,28,14)  f32
    float* out          = (float*)d_out;           // (10752,10752) f32
    unsigned short* Fh  = (unsigned short*)d_ws;   // (28,16,96) bf16 = 86KB

    font_prep<<<(CH * 16 * KP + 255) / 256, 256, 0, stream>>>(font, Fh);

    const int blocks = (ROWS * COLS) / 64;         // 4608 one-wave blocks
    diffrender_v8<<<blocks, 64, 0, stream>>>(logits, Fh, out);
}

// Round 9
// 125.468 us; speedup vs baseline: 1.0929x; 1.0929x over previous
//
#include <hip/hip_runtime.h>
#include <hip/hip_bf16.h>

// DiffRenderer v9: v6 loop structure + occupancy push (the one unablated var).
// v5(fences)=v6(none)=v7(coalesced loads)=122us at ~2.25-3 waves/SIMD; theory:
// softmax-phase stalls uncovered -> write-active ~60% of 6.7TB/s fill rate.
// v9: ROW_U 104->72 (font k>=69 is zero => A-frag ks=2 may read clamped finite
// garbage, product still 0), 64-thr blocks, launch_bounds(64,4) -> 9216B LDS,
// 16 blocks/CU = 16 waves/CU (~50% occ). Loop: 1 row/iter, staged f4 stores.
#define ROWS 384
#define COLS 768
#define NCH  69
#define CH   28
#define CW   14
#define KP   96             // font K padded to 3 k-steps of 32 (zeros past 68)
#define IMG_W 10752
#define ROW_U 72            // prob-row stride in ushorts (144B, 16B-aligned)

typedef __attribute__((ext_vector_type(8))) short bfrag;   // 8 bf16 (4 VGPR)
typedef __attribute__((ext_vector_type(4))) float f32x4;   // C/D frag

__device__ __forceinline__ unsigned bf16bits(float x) {
    unsigned b = __float_as_uint(x);
    b += 0x7FFFu + ((b >> 16) & 1u);   // RTNE
    return b >> 16;
}

// ---- kernel 1: font (69,28,14) f32 -> Fh[28][16][96] bf16 (zero-padded) ----
__global__ __launch_bounds__(256)
void font_prep(const float* __restrict__ font, unsigned short* __restrict__ Fh) {
    int idx = blockIdx.x * 256 + threadIdx.x;        // 28*16*96 = 43008
    if (idx >= CH * 16 * KP) return;
    int k  = idx % KP;
    int hw = idx / KP;
    int w  = hw % 16, h = hw / 16;
    float v = (w < CW && k < NCH) ? font[k * (CH * CW) + h * CW + w] : 0.f;
    Fh[idx] = (unsigned short)bf16bits(v);
}

// ---- kernel 2: softmax + MFMA blend + row-coalesced assemble ----
__global__ __launch_bounds__(64, 4)
void diffrender_v9(const float* __restrict__ logits,       // (294912,69) f32
                   const unsigned short* __restrict__ Fh,  // (28,16,96) bf16
                   float* __restrict__ out)                // (10752,10752) f32
{
    __shared__ __align__(16) unsigned short Pa[64 * ROW_U]; // 9216 B

    const int lane = threadIdx.x;
    const int bid  = blockIdx.x;
    const int r    = bid / 12;                 // cell row (12 blocks/row)
    const int cb   = (bid % 12) * 64;          // first cell col of this block
    const int cell = bid * 64 + lane;

    // ---- per-thread softmax over 69 logits ----
    const float* lp = logits + (size_t)cell * NCH;
    float e[NCH];
    float m = -INFINITY;
#pragma unroll
    for (int n = 0; n < NCH; ++n) { e[n] = lp[n]; m = fmaxf(m, e[n]); }
    float s = 0.f;
#pragma unroll
    for (int n = 0; n < NCH; ++n) { e[n] = __expf(e[n] - m); s += e[n]; }
    const float inv = 1.f / s;

    // ---- pack probs bf16 -> LDS row `lane` (72 ushorts: k0..68 + 3 zeros) ----
    unsigned* prow = (unsigned*)&Pa[(size_t)lane * ROW_U];
#pragma unroll
    for (int i = 0; i < 34; ++i)
        prow[i] = bf16bits(e[2 * i] * inv) | (bf16bits(e[2 * i + 1] * inv) << 16);
    prow[34] = bf16bits(e[68] * inv);          // k68 | 0
    prow[35] = 0;                              // k70,71 = 0

    // ---- A-frags (probs): 4 M-tiles x 3 k-steps ----
    const int w15   = lane & 15;
    const int g     = lane >> 4;
    const int kgrp  = g * 8;
    const int crow4 = g * 4;
    bfrag a[4][3];
#pragma unroll
    for (int mt = 0; mt < 4; ++mt) {
        const size_t base = (size_t)(mt * 16 + w15) * ROW_U;
        a[mt][0] = *(const bfrag*)&Pa[base + kgrp];
        a[mt][1] = *(const bfrag*)&Pa[base + 32 + kgrp];
        // ks=2: all lane-groups read k64..71 (finite); font k>=69 is 0, and
        // for g>=1 the font slice k72..95 is all-zero -> product 0 regardless.
        a[mt][2] = *(const bfrag*)&Pa[base + 64];
    }

    // prob buffer dead after a-frag reads -> reuse as f32 stage (1 row x 896)
    float* stage = (float*)Pa;

    // ---- h loop: one image row per iter, double-buffered B (font) ----
    const unsigned short* fb = Fh + (size_t)w15 * KP + kgrp;
    bfrag bcur[3], bnxt[3];
#pragma unroll
    for (int ks = 0; ks < 3; ++ks)
        bcur[ks] = *(const bfrag*)(fb + ks * 32);

#pragma unroll 1
    for (int h = 0; h < CH; ++h) {
        if (h + 1 < CH) {
            const unsigned short* fn = fb + (size_t)(h + 1) * 16 * KP;
#pragma unroll
            for (int ks = 0; ks < 3; ++ks)
                bnxt[ks] = *(const bfrag*)(fn + ks * 32);
        }

        f32x4 acc[4] = {f32x4{0,0,0,0}, f32x4{0,0,0,0}, f32x4{0,0,0,0}, f32x4{0,0,0,0}};
#pragma unroll
        for (int mt = 0; mt < 4; ++mt)
#pragma unroll
            for (int ks = 0; ks < 3; ++ks)
                acc[mt] = __builtin_amdgcn_mfma_f32_16x16x32_bf16(a[mt][ks], bcur[ks], acc[mt], 0, 0, 0);

        // transpose through LDS: stage[cell_local*14 + w]
        if (w15 < CW) {
#pragma unroll
            for (int mt = 0; mt < 4; ++mt)
#pragma unroll
                for (int j = 0; j < 4; ++j)
                    stage[(mt * 16 + crow4 + j) * CW + w15] = acc[mt][j];
        }

        // coalesced stores: 896 floats = 224 float4 (4 masked insts)
        float4* o4 = (float4*)(out + (size_t)(r * CH + h) * IMG_W + (size_t)cb * CW);
        const float4* s4 = (const float4*)stage;
#pragma unroll
        for (int i = 0; i < 4; ++i) {
            const int idx = i * 64 + lane;
            if (idx < 224) o4[idx] = s4[idx];
        }

#pragma unroll
        for (int ks = 0; ks < 3; ++ks) bcur[ks] = bnxt[ks];
    }
}

extern "C" void kernel_launch(void* const* d_in, const int* in_sizes, int n_in,
                              void* d_out, int out_size, void* d_ws, size_t ws_size,
                              hipStream_t stream) {
    const float* logits = (const float*)d_in[0];   // (384,768,69) f32
    const float* font   = (const float*)d_in[1];   // (69,28,14)  f32
    float* out          = (float*)d_out;           // (10752,10752) f32
    unsigned short* Fh  = (unsigned short*)d_ws;   // (28,16,96) bf16 = 86KB

    font_prep<<<(CH * 16 * KP + 255) / 256, 256, 0, stream>>>(font, Fh);

    const int blocks = (ROWS * COLS) / 64;         // 4608 one-wave blocks
    diffrender_v9<<<blocks, 64, 0, stream>>>(logits, Fh, out);
}

// Round 10
// 124.551 us; speedup vs baseline: 1.1009x; 1.0074x over previous
//
#include <hip/hip_runtime.h>
#include <hip/hip_bf16.h>

// DiffRenderer v10: operand-swapped MFMA (v8 layout) + LDS write-combine
// stage (v9 stores) + XCD swizzle.
// Ledger: fences null, load-coalescing null, occupancy null, direct-scatter
// stores -15us, five structures pinned ~122us. Largest unablated per-CU item:
// LDS pipe (~30us: 14 ds_write_b32 + 4 ds_read_b128 per wave-iter). Swapped
// D-layout (lane = 4 consecutive pixels of one cell) cuts stage writes to
// ~7 ds_write_b64; ROW_U=80 zero-pads k69..79 so B-side pad reads stay
// in-bounds (Pa max idx 5119/5120) and multiply only zero font rows.
#define ROWS 384
#define COLS 768
#define NCH  69
#define CH   28
#define CW   14
#define KP   96             // font K padded (zeros past 68)
#define IMG_W 10752
#define ROW_U 80            // prob-row stride in ushorts (160B; k69..79 = 0)

typedef __attribute__((ext_vector_type(8))) short bfrag;   // 8 bf16 (4 VGPR)
typedef __attribute__((ext_vector_type(4))) float f32x4;   // C/D frag

__device__ __forceinline__ unsigned bf16bits(float x) {
    unsigned b = __float_as_uint(x);
    b += 0x7FFFu + ((b >> 16) & 1u);   // RTNE
    return b >> 16;
}

// ---- kernel 1: font (69,28,14) f32 -> Fh[28][16][96] bf16 (zero-padded) ----
__global__ __launch_bounds__(256)
void font_prep(const float* __restrict__ font, unsigned short* __restrict__ Fh) {
    int idx = blockIdx.x * 256 + threadIdx.x;        // 28*16*96 = 43008
    if (idx >= CH * 16 * KP) return;
    int k  = idx % KP;
    int hw = idx / KP;
    int w  = hw % 16, h = hw / 16;
    float v = (w < CW && k < NCH) ? font[k * (CH * CW) + h * CW + w] : 0.f;
    Fh[idx] = (unsigned short)bf16bits(v);
}

// ---- kernel 2: softmax + swapped MFMA + write-combined assemble ----
__global__ __launch_bounds__(64, 4)
void diffrender_v10(const float* __restrict__ logits,       // (294912,69) f32
                    const unsigned short* __restrict__ Fh,  // (28,16,96) bf16
                    float* __restrict__ out)                // (10752,10752) f32
{
    __shared__ __align__(16) unsigned short Pa[64 * ROW_U]; // 10240 B

    const int lane = threadIdx.x;
    // bijective XCD-chunked swizzle: 4608 = 8 XCDs x 576
    const int bid0 = blockIdx.x;
    const int bid  = (bid0 & 7) * 576 + (bid0 >> 3);
    const int r    = bid / 12;                 // cell row (12 blocks/row)
    const int cb   = (bid % 12) * 64;          // first cell col of this block
    const int cell = bid * 64 + lane;

    // ---- per-thread softmax over 69 logits ----
    const float* lp = logits + (size_t)cell * NCH;
    float e[NCH];
    float m = -INFINITY;
#pragma unroll
    for (int n = 0; n < NCH; ++n) { e[n] = lp[n]; m = fmaxf(m, e[n]); }
    float s = 0.f;
#pragma unroll
    for (int n = 0; n < NCH; ++n) { e[n] = __expf(e[n] - m); s += e[n]; }
    const float inv = 1.f / s;

    // ---- pack probs bf16 -> LDS row `lane` (80 ushorts: k0..68 + zeros) ----
    unsigned* prow = (unsigned*)&Pa[(size_t)lane * ROW_U];
#pragma unroll
    for (int i = 0; i < 34; ++i)
        prow[i] = bf16bits(e[2 * i] * inv) | (bf16bits(e[2 * i + 1] * inv) << 16);
    prow[34] = bf16bits(e[68] * inv);          // k68 | k69=0
#pragma unroll
    for (int i = 35; i < 40; ++i) prow[i] = 0; // k70..79 = 0

    // ---- B-frags (probs): 4 cell-groups x 3 k-steps, held all kernel ----
    const int c15   = lane & 15;               // B col = cell within group
    const int g     = lane >> 4;
    const int kgrp  = g * 8;                   // k-slice base
    const int crow4 = g * 4;                   // D row base = w base
    bfrag b[4][3];
#pragma unroll
    for (int mt = 0; mt < 4; ++mt)
#pragma unroll
        for (int ks = 0; ks < 3; ++ks)
            b[mt][ks] = *(const bfrag*)&Pa[(size_t)(mt * 16 + c15) * ROW_U + ks * 32 + kgrp];

    // prob buffer dead (b in regs) -> reuse as f32 stage (64 cells x 14 px)
    float* stage = (float*)Pa;

    // ---- h loop: A = font tile (rows = w, zero-padded), double-buffered ----
    const unsigned short* fb = Fh + (size_t)c15 * KP + kgrp;
    bfrag acur[3], anxt[3];
#pragma unroll
    for (int ks = 0; ks < 3; ++ks)
        acur[ks] = *(const bfrag*)(fb + ks * 32);

#pragma unroll 1
    for (int h = 0; h < CH; ++h) {
        if (h + 1 < CH) {
            const unsigned short* fn = fb + (size_t)(h + 1) * 16 * KP;
#pragma unroll
            for (int ks = 0; ks < 3; ++ks)
                anxt[ks] = *(const bfrag*)(fn + ks * 32);
        }

        f32x4 acc[4] = {f32x4{0,0,0,0}, f32x4{0,0,0,0}, f32x4{0,0,0,0}, f32x4{0,0,0,0}};
#pragma unroll
        for (int mt = 0; mt < 4; ++mt)
#pragma unroll
            for (int ks = 0; ks < 3; ++ks)
                acc[mt] = __builtin_amdgcn_mfma_f32_16x16x32_bf16(acur[ks], b[mt][ks], acc[mt], 0, 0, 0);

        // write-combine: lane owns 4 consecutive pixels of one cell ->
        // 2x ds_write_b64 per mt (crow4==12 skips w14,15 pad; acc there = 0)
#pragma unroll
        for (int mt = 0; mt < 4; ++mt) {
            float* p = stage + (mt * 16 + c15) * CW + crow4;   // 8B-aligned
            *(float2*)p = make_float2(acc[mt][0], acc[mt][1]);
            if (crow4 < 12)
                *(float2*)(p + 2) = make_float2(acc[mt][2], acc[mt][3]);
        }

        // coalesced stores: 896 floats = 224 float4 (4 masked insts)
        float4* o4 = (float4*)(out + (size_t)(r * CH + h) * IMG_W + (size_t)cb * CW);
        const float4* s4 = (const float4*)stage;
#pragma unroll
        for (int i = 0; i < 4; ++i) {
            const int idx = i * 64 + lane;
            if (idx < 224) o4[idx] = s4[idx];
        }

#pragma unroll
        for (int ks = 0; ks < 3; ++ks) acur[ks] = anxt[ks];
    }
}

extern "C" void kernel_launch(void* const* d_in, const int* in_sizes, int n_in,
                              void* d_out, int out_size, void* d_ws, size_t ws_size,
                              hipStream_t stream) {
    const float* logits = (const float*)d_in[0];   // (384,768,69) f32
    const float* font   = (const float*)d_in[1];   // (69,28,14)  f32
    float* out          = (float*)d_out;           // (10752,10752) f32
    unsigned short* Fh  = (unsigned short*)d_ws;   // (28,16,96) bf16 = 86KB

    font_prep<<<(CH * 16 * KP + 255) / 256, 256, 0, stream>>>(font, Fh);

    const int blocks = (ROWS * COLS) / 64;         // 4608 one-wave blocks
    diffrender_v10<<<blocks, 64, 0, stream>>>(logits, Fh, out);
}

// Round 12
// 107.927 us; speedup vs baseline: 1.2705x; 1.1540x over previous
//
#include <hip/hip_runtime.h>
#include <hip/hip_bf16.h>

// DiffRenderer v11b: v6 structure VERBATIM + nontemporal output stores.
// (v11 failed to compile: __builtin_nontemporal_store rejects HIP float4
// struct; use clang ext_vector_type f32x4 instead.)
// Ledger through r10: fences null, load-coalescing null, occupancy null,
// LDS write-combine null, XCD swizzle null, direct-scatter stores -15us.
// Six structures pinned at 122-125us = ~6.2 B/cyc/CU writes vs fill 11.2.
// Hypothesis: store stream write-allocates in L2 (100% thrash of 4MB/XCD)
// while competing with the logits read stream; nt stores bypass allocation.
#define ROWS 384
#define COLS 768
#define NCH  69
#define CH   28
#define CW   14
#define KP   96             // K padded to 3 MFMA k-steps of 32
#define IMG_W 10752
#define ROW_U 104           // prob-row stride in ushorts (208B, 16B-aligned)

typedef __attribute__((ext_vector_type(8))) short bfrag;   // 8 bf16 (4 VGPR)
typedef __attribute__((ext_vector_type(4))) float f32x4;   // C/D frag / stores

__device__ __forceinline__ unsigned bf16bits(float x) {
    unsigned b = __float_as_uint(x);
    b += 0x7FFFu + ((b >> 16) & 1u);   // RTNE
    return b >> 16;
}

// ---- kernel 1: font (69,28,14) f32 -> Fh[28][16][96] bf16 ----
__global__ __launch_bounds__(256)
void font_prep(const float* __restrict__ font, unsigned short* __restrict__ Fh) {
    int idx = blockIdx.x * 256 + threadIdx.x;        // 28*16*96 = 43008
    if (idx >= CH * 16 * KP) return;
    int k  = idx % KP;
    int hw = idx / KP;
    int w  = hw % 16, h = hw / 16;
    float v = (w < CW && k < NCH) ? font[k * (CH * CW) + h * CW + w] : 0.f;
    Fh[idx] = (unsigned short)bf16bits(v);
}

// ---- kernel 2: softmax + MFMA blend + row-coalesced nt-store assemble ----
__global__ __launch_bounds__(128, 3)
void diffrender_v11(const float* __restrict__ logits,       // (294912,69) f32
                    const unsigned short* __restrict__ Fh,  // (28,16,96) bf16
                    float* __restrict__ out)                // (10752,10752) f32
{
    __shared__ __align__(16) unsigned short smem[2][64 * ROW_U]; // 26.6KB, per-wave

    const int tid  = threadIdx.x;
    const int lane = tid & 63;
    const int wv   = tid >> 6;
    const int cell = blockIdx.x * 128 + tid;         // row-major over (384,768)
    const int r    = blockIdx.x / 6;                 // cell row (6 blocks/row)
    const int cb   = (blockIdx.x % 6) * 128;         // first cell col of block

    // ---- per-thread softmax over 69 logits ----
    const float* lp = logits + (size_t)cell * NCH;
    float e[NCH];
    float m = -INFINITY;
#pragma unroll
    for (int n = 0; n < NCH; ++n) { e[n] = lp[n]; m = fmaxf(m, e[n]); }
    float s = 0.f;
#pragma unroll
    for (int n = 0; n < NCH; ++n) { e[n] = __expf(e[n] - m); s += e[n]; }
    const float inv = 1.f / s;

    // ---- pack probs bf16 -> per-wave LDS row (k 0..95, zero-padded) ----
    unsigned* prow = (unsigned*)&smem[wv][(size_t)lane * ROW_U];
#pragma unroll
    for (int i = 0; i < 34; ++i)
        prow[i] = bf16bits(e[2 * i] * inv) | (bf16bits(e[2 * i + 1] * inv) << 16);
    prow[34] = bf16bits(e[68] * inv);
#pragma unroll
    for (int i = 35; i < 48; ++i) prow[i] = 0;

    // ---- this wave's 12 A-fragments (4 M-tiles x 3 k-steps) ----
    const int w15   = lane & 15;
    const int kgrp  = (lane >> 4) * 8;
    const int crow4 = (lane >> 4) * 4;
    bfrag a[4][3];
#pragma unroll
    for (int mt = 0; mt < 4; ++mt)
#pragma unroll
        for (int ks = 0; ks < 3; ++ks)
            a[mt][ks] = *(const bfrag*)&smem[wv][(size_t)(mt * 16 + w15) * ROW_U + ks * 32 + kgrp];

    // prob buffer dead after a-frag reads -> reuse as f32 stage (2 rows x 896)
    float* stage = (float*)&smem[wv][0];

    // ---- h loop: TWO image rows per iteration, double-buffered B ----
    const unsigned short* fb = Fh + (size_t)w15 * KP + kgrp;
    bfrag bcur[2][3], bnxt[2][3];
#pragma unroll
    for (int hh = 0; hh < 2; ++hh)
#pragma unroll
        for (int ks = 0; ks < 3; ++ks)
            bcur[hh][ks] = *(const bfrag*)(fb + (size_t)(hh * 16) * KP + ks * 32);

#pragma unroll 1
    for (int h2 = 0; h2 < CH / 2; ++h2) {
        const int h = 2 * h2;
        if (h2 + 1 < CH / 2) {
            const unsigned short* fn = fb + (size_t)((h + 2) * 16) * KP;
#pragma unroll
            for (int hh = 0; hh < 2; ++hh)
#pragma unroll
                for (int ks = 0; ks < 3; ++ks)
                    bnxt[hh][ks] = *(const bfrag*)(fn + (size_t)(hh * 16) * KP + ks * 32);
        }

        f32x4 acc[2][4];
#pragma unroll
        for (int hh = 0; hh < 2; ++hh)
#pragma unroll
            for (int mt = 0; mt < 4; ++mt)
                acc[hh][mt] = f32x4{0, 0, 0, 0};
#pragma unroll
        for (int hh = 0; hh < 2; ++hh)
#pragma unroll
            for (int mt = 0; mt < 4; ++mt)
#pragma unroll
                for (int ks = 0; ks < 3; ++ks)
                    acc[hh][mt] = __builtin_amdgcn_mfma_f32_16x16x32_bf16(
                        a[mt][ks], bcur[hh][ks], acc[hh][mt], 0, 0, 0);

        // transpose through per-wave LDS: stage[hh][cell_local*14 + w]
        if (w15 < CW) {
#pragma unroll
            for (int hh = 0; hh < 2; ++hh)
#pragma unroll
                for (int mt = 0; mt < 4; ++mt)
#pragma unroll
                    for (int j = 0; j < 4; ++j)
                        stage[hh * 896 + (mt * 16 + crow4 + j) * CW + w15] = acc[hh][mt][j];
        }

        // coalesced NONTEMPORAL stores: per row, 224 f32x4 (4 masked insts)
#pragma unroll
        for (int hh = 0; hh < 2; ++hh) {
            f32x4* o4 = (f32x4*)(out + (size_t)(r * CH + h + hh) * IMG_W
                                     + (size_t)(cb + wv * 64) * CW);
            const f32x4* s4 = (const f32x4*)(stage + hh * 896);
#pragma unroll
            for (int i = 0; i < 4; ++i) {
                const int idx = i * 64 + lane;
                if (idx < 224) __builtin_nontemporal_store(s4[idx], &o4[idx]);
            }
        }

#pragma unroll
        for (int hh = 0; hh < 2; ++hh)
#pragma unroll
            for (int ks = 0; ks < 3; ++ks)
                bcur[hh][ks] = bnxt[hh][ks];
    }
}

extern "C" void kernel_launch(void* const* d_in, const int* in_sizes, int n_in,
                              void* d_out, int out_size, void* d_ws, size_t ws_size,
                              hipStream_t stream) {
    const float* logits = (const float*)d_in[0];   // (384,768,69) f32
    const float* font   = (const float*)d_in[1];   // (69,28,14)  f32
    float* out          = (float*)d_out;           // (10752,10752) f32
    unsigned short* Fh  = (unsigned short*)d_ws;   // (28,16,96) bf16 = 86KB

    font_prep<<<(CH * 16 * KP + 255) / 256, 256, 0, stream>>>(font, Fh);

    const int blocks = (ROWS * COLS) / 128;        // 2304
    diffrender_v11<<<blocks, 128, 0, stream>>>(logits, Fh, out);
}